// Round 1
// baseline (421.753 us; speedup 1.0000x reference)
//
#include <hip/hip_runtime.h>

#define NN 8192
#define FIN 128
#define FOUT 64
#define NSLICE 4
#define JSLICE (NN / NSLICE)
#define JTILE 256
#define NT (JSLICE / JTILE)   // 8 tiles per block
#define PT_LD 264             // Pt row stride in shorts: 256 + 8 pad
#define MWPR 128              // u64 mask words per adj row (8192 bits)
#define LOG2E 1.4426950408889634f

typedef __attribute__((ext_vector_type(8))) short short8;
typedef __attribute__((ext_vector_type(4))) float floatx4;
typedef __attribute__((ext_vector_type(4))) unsigned short ushort4v;
typedef unsigned long long u64;

__device__ __forceinline__ unsigned short f32_to_bf16(float f) {
    unsigned int u = __float_as_uint(f);
    return (unsigned short)((u + 0x7FFFu + ((u >> 16) & 1u)) >> 16);
}
__device__ __forceinline__ float bf16_to_f32(unsigned short b) {
    return __uint_as_float(((unsigned int)b) << 16);
}

// Kernel 1: wh = h @ W (fp32). Writes whB DIRECTLY in MFMA B-fragment order
// (bf16), plus src/dst PRE-SCALED by log2(e) so gat_attn uses bare v_exp_f32:
// exp(leaky(x)) == exp2(leaky(x*log2e)) since log2e > 0 commutes with max().
__global__ __launch_bounds__(256) void gat_prep(
    const float* __restrict__ h,      // 8192x128
    const float* __restrict__ edge,   // 8192x1
    const float* __restrict__ weight, // 128x64
    const float* __restrict__ att,    // 192x1
    const float* __restrict__ wedge,  // 1x64
    unsigned short* __restrict__ whB, // bf16 fragment-order (1 MB)
    float* __restrict__ src,          // 8192 (scaled by log2e)
    float* __restrict__ dst)          // 8192 (scaled by log2e)
{
    __shared__ float wl[FIN * FOUT];   // 32 KB
    __shared__ float hl[16 * FIN];     // 8 KB
    const int tid = threadIdx.x;
    const int b = blockIdx.x;

    const float4* w4 = (const float4*)weight;
    float4* wl4 = (float4*)wl;
    for (int idx = tid; idx < FIN * FOUT / 4; idx += 256) wl4[idx] = w4[idx];
    const float4* h4 = (const float4*)(h + (size_t)b * 16 * FIN);
    float4* hl4 = (float4*)hl;
    for (int idx = tid; idx < 16 * FIN / 4; idx += 256) hl4[idx] = h4[idx];
    __syncthreads();

    const int wave = tid >> 6;
    const int lane = tid & 63;
    float acc[4] = {0.f, 0.f, 0.f, 0.f};
    for (int c = 0; c < FIN; ++c) {
        const float wv = wl[c * FOUT + lane];
#pragma unroll
        for (int r = 0; r < 4; ++r)
            acc[r] = fmaf(hl[(wave * 4 + r) * FIN + c], wv, acc[r]);
    }
    const int row0 = b * 16 + wave * 4;

    // ---- whB fragment-order store (layout verified in prior session) ----
    {
        const int T = b >> 2;
        const int o = (b & 3) * 16 + wave * 4;     // tile-local row of r=0
        const int c = o >> 5;
        const int quad = (o >> 3) & 3;
        const int i0 = o & 7;                      // 0 or 4
        const int q = lane >> 4, col = lane & 15;
        const int f = T * 8 + q * 2 + c;
        const int elem = f * 64 + quad * 16 + col;
        ushort4v wb;
#pragma unroll
        for (int r = 0; r < 4; ++r) wb[r] = f32_to_bf16(acc[r]);
        *(ushort4v*)(whB + (size_t)elem * 8 + i0) = wb;
    }

    const float a1 = att[lane];
    const float a2 = att[FOUT + lane];
    float t3 = wedge[lane] * att[2 * FOUT + lane];
#pragma unroll
    for (int off = 32; off > 0; off >>= 1) t3 += __shfl_xor(t3, off, 64);

#pragma unroll
    for (int r = 0; r < 4; ++r) {
        float t1 = acc[r] * a1;
        float t2 = acc[r] * a2;
#pragma unroll
        for (int off = 32; off > 0; off >>= 1) {
            t1 += __shfl_xor(t1, off, 64);
            t2 += __shfl_xor(t2, off, 64);
        }
        if (lane == 0) {
            src[row0 + r] = (t1 + edge[row0 + r] * t3) * LOG2E;
            dst[row0 + r] = t2 * LOG2E;
        }
    }
}

// Kernel 1b: compress adj (256 MB int32) -> bitmask (8 MB). Pure streaming,
// trivially BW-bound. Layout: word (4g+c) of a row, bit l = adj[256g + 4l + c]
// (ballot order from per-lane int4 loads) -- matches gat_attn's lane->j map.
__global__ __launch_bounds__(256) void gat_mask(
    const int* __restrict__ adj, u64* __restrict__ mask)
{
    const int wave = threadIdx.x >> 6, lane = threadIdx.x & 63;
    const int row = blockIdx.x * 4 + wave;
    const int4* a4 = (const int4*)(adj + (size_t)row * NN);
    u64* mrow = mask + (size_t)row * MWPR;
#pragma unroll 4
    for (int g = 0; g < 32; ++g) {
        const int4 v = a4[g * 64 + lane];
        const u64 b0 = __ballot(v.x > 0);
        const u64 b1 = __ballot(v.y > 0);
        const u64 b2 = __ballot(v.z > 0);
        const u64 b3 = __ballot(v.w > 0);
        if (lane < 4) {
            const u64 bb = lane == 0 ? b0 : lane == 1 ? b1 : lane == 2 ? b2 : b3;
            mrow[g * 4 + lane] = bb;
        }
    }
}

// Kernel 2: fused masked-softmax-numerator + P@Wh via MFMA.
// All inner-loop inputs are now L2/L3-resident (mask 8 MB, dst 32 KB, whB
// 1 MB): no HBM latency on the critical path. Per tile: exp-compute from
// prefetched regs -> LDS (double-buffered); B-fragment loads issued BEFORE
// the next-tile prefetch (older in vmcnt order => MFMA waits drain only the
// L2-hit bq loads, prefetch stays in flight); raw lgkmcnt(0)+s_barrier; 8
// MFMAs on dual accumulators (breaks the dependency chain).
__global__ __launch_bounds__(256) void gat_attn(
    const u64* __restrict__ mask,
    const unsigned short* __restrict__ whB,
    const float* __restrict__ src,
    const float* __restrict__ dst,
    float* __restrict__ ws_acc,      // [4][8192][64]
    float* __restrict__ ws_l)        // [4][8192]
{
    __shared__ unsigned short Pt[2][16][PT_LD];   // 16.9 KB
    const int wave = threadIdx.x >> 6;
    const int lane = threadIdx.x & 63;
    const int i0 = blockIdx.x * 16;
    const int s  = blockIdx.y;
    const size_t jbase = (size_t)s * JSLICE;
    const int m = lane & 15, quad = lane >> 4;

    float sr[4];
    const u64* mp[4];
#pragma unroll
    for (int r = 0; r < 4; ++r) {
        const int row = i0 + wave * 4 + r;
        sr[r] = src[row];
        mp[r] = mask + (size_t)row * MWPR + s * (MWPR / NSLICE);
    }
    const float4* dst4 = (const float4*)(dst + jbase);
    float lsum[4] = {0.f, 0.f, 0.f, 0.f};
    floatx4 acc0 = {0.f, 0.f, 0.f, 0.f};
    floatx4 acc1 = {0.f, 0.f, 0.f, 0.f};

    // Preload tile 0
    u64 mw[4][4];
    float4 dv = dst4[lane];
#pragma unroll
    for (int r = 0; r < 4; ++r)
#pragma unroll
        for (int c = 0; c < 4; ++c) mw[r][c] = mp[r][c];

    for (int t = 0; t < NT; ++t) {
        const int buf = t & 1;

        // ---- exp-compute current tile from registers; write LDS
#pragma unroll
        for (int r = 0; r < 4; ++r) {
            const unsigned int b0 = (unsigned int)(mw[r][0] >> lane) & 1u;
            const unsigned int b1 = (unsigned int)(mw[r][1] >> lane) & 1u;
            const unsigned int b2 = (unsigned int)(mw[r][2] >> lane) & 1u;
            const unsigned int b3 = (unsigned int)(mw[r][3] >> lane) & 1u;
            ushort4v pv;
            float v, p;
            v = sr[r] + dv.x; v = fmaxf(v, 0.2f * v);
            p = b0 ? __builtin_amdgcn_exp2f(v) : 0.f; pv.x = f32_to_bf16(p);
            v = sr[r] + dv.y; v = fmaxf(v, 0.2f * v);
            p = b1 ? __builtin_amdgcn_exp2f(v) : 0.f; pv.y = f32_to_bf16(p);
            v = sr[r] + dv.z; v = fmaxf(v, 0.2f * v);
            p = b2 ? __builtin_amdgcn_exp2f(v) : 0.f; pv.z = f32_to_bf16(p);
            v = sr[r] + dv.w; v = fmaxf(v, 0.2f * v);
            p = b3 ? __builtin_amdgcn_exp2f(v) : 0.f; pv.w = f32_to_bf16(p);
            lsum[r] += bf16_to_f32(pv.x) + bf16_to_f32(pv.y)
                     + bf16_to_f32(pv.z) + bf16_to_f32(pv.w);
            *(ushort4v*)&Pt[buf][wave * 4 + r][4 * lane] = pv;
        }

        // ---- B-fragment loads for THIS tile (L2-hit); issued before the
        // prefetch so MFMA's vmcnt waits never drain next-tile loads.
        const int jt0 = (int)((jbase + (size_t)t * JTILE) >> 6);
        short8 bq[8];
#pragma unroll
        for (int kk = 0; kk < 8; ++kk) {
            const int f = (jt0 + (kk >> 1)) * 8 + wave * 2 + (kk & 1);
            bq[kk] = *((const short8*)whB + (size_t)f * 64 + lane);
        }
        __builtin_amdgcn_sched_barrier(0);   // pin: bq issue stays here

        // ---- prefetch next tile's mask words + dst (newest; stay in flight)
        if (t + 1 < NT) {
            dv = dst4[(t + 1) * (JTILE / 4) + lane];
#pragma unroll
            for (int r = 0; r < 4; ++r)
#pragma unroll
                for (int c = 0; c < 4; ++c) mw[r][c] = mp[r][(t + 1) * 4 + c];
        }

        // ---- LDS-visibility barrier only (no vmcnt drain)
        __builtin_amdgcn_s_waitcnt(0xC07F);   // lgkmcnt(0)
        __builtin_amdgcn_s_barrier();

        // ---- 8 MFMAs over K=256, dual accumulators
#pragma unroll
        for (int kk = 0; kk < 8; ++kk) {
            const short8 a = *(const short8*)&Pt[buf][m][kk * 32 + quad * 8];
            if (kk & 1)
                acc1 = __builtin_amdgcn_mfma_f32_16x16x32_bf16(a, bq[kk], acc1, 0, 0, 0);
            else
                acc0 = __builtin_amdgcn_mfma_f32_16x16x32_bf16(a, bq[kk], acc0, 0, 0, 0);
        }
    }

#pragma unroll
    for (int r = 0; r < 4; ++r) {
#pragma unroll
        for (int off = 32; off > 0; off >>= 1)
            lsum[r] += __shfl_xor(lsum[r], off, 64);
    }
    if (lane == 0) {
#pragma unroll
        for (int r = 0; r < 4; ++r)
            ws_l[(size_t)s * NN + i0 + wave * 4 + r] = lsum[r];
    }

    const floatx4 acc = acc0 + acc1;
    // C/D layout: col = lane&15, row = quad*4 + reg
#pragma unroll
    for (int reg = 0; reg < 4; ++reg) {
        const int row = quad * 4 + reg;
        ws_acc[(size_t)s * (NN * FOUT) + (size_t)(i0 + row) * FOUT + wave * 16 + m] = acc[reg];
    }
}

// Kernel 3: reduce 4 j-slices, divide by softmax denom, ELU. float4-vectorized.
__global__ __launch_bounds__(256) void gat_finish(
    const float* __restrict__ ws_acc, const float* __restrict__ ws_l,
    float* __restrict__ out)
{
    const int idx = blockIdx.x * 256 + threadIdx.x;   // float4 index, 0..NN*16-1
    const int i = idx >> 4;                            // 16 float4 per row
    float4 a = ((const float4*)ws_acc)[idx];
    float l = ws_l[i];
#pragma unroll
    for (int s = 1; s < NSLICE; ++s) {
        const float4 b = ((const float4*)ws_acc)[(size_t)s * (NN * 16) + idx];
        a.x += b.x; a.y += b.y; a.z += b.z; a.w += b.w;
        l += ws_l[(size_t)s * NN + i];
    }
    float4 o;
    float v;
    v = a.x / l; o.x = (v > 0.f) ? v : expm1f(v);
    v = a.y / l; o.y = (v > 0.f) ? v : expm1f(v);
    v = a.z / l; o.z = (v > 0.f) ? v : expm1f(v);
    v = a.w / l; o.w = (v > 0.f) ? v : expm1f(v);
    ((float4*)out)[idx] = o;
}

extern "C" void kernel_launch(void* const* d_in, const int* in_sizes, int n_in,
                              void* d_out, int out_size, void* d_ws, size_t ws_size,
                              hipStream_t stream) {
    const float* h      = (const float*)d_in[0];
    const float* edge   = (const float*)d_in[1];
    const int*   adj    = (const int*)d_in[2];
    const float* weight = (const float*)d_in[3];
    const float* att    = (const float*)d_in[4];
    const float* wedge  = (const float*)d_in[5];
    float* out = (float*)d_out;

    unsigned short* whB = (unsigned short*)d_ws;          // 1 MB bf16 frags
    float* src    = (float*)(whB + (size_t)NN * FOUT);    // 8192
    float* dst    = src + NN;                             // 8192
    float* ws_l   = dst + NN;                             // 4*8192
    float* ws_acc = ws_l + (size_t)NSLICE * NN;           // 8 MB
    u64*   mask   = (u64*)(ws_acc + (size_t)NSLICE * NN * FOUT);  // 8 MB

    gat_prep<<<NN / 16, 256, 0, stream>>>(h, edge, weight, att, wedge, whB, src, dst);
    gat_mask<<<NN / 4, 256, 0, stream>>>(adj, mask);
    gat_attn<<<dim3(NN / 16, NSLICE), 256, 0, stream>>>(mask, whB, src, dst, ws_acc, ws_l);
    gat_finish<<<NN * 16 / 256, 256, 0, stream>>>(ws_acc, ws_l, out);
}

// Round 2
// 415.688 us; speedup vs baseline: 1.0146x; 1.0146x over previous
//
#include <hip/hip_runtime.h>

#define NN 8192
#define FIN 128
#define FOUT 64
#define NSLICE 4
#define JSLICE (NN / NSLICE)      // 2048 j per block
#define WJ (JSLICE / 4)           // 512 j per wave
#define NMT (WJ / 64)             // 8 microtiles of 64 j per wave
#define MWPR 128                  // u64 mask words per adj row (8192 bits)
#define LOG2E 1.4426950408889634f

typedef __attribute__((ext_vector_type(8))) short short8;
typedef __attribute__((ext_vector_type(4))) float floatx4;
typedef __attribute__((ext_vector_type(4))) unsigned short ushort4v;
typedef unsigned long long u64;

__device__ __forceinline__ unsigned short f32_to_bf16(float f) {
    unsigned int u = __float_as_uint(f);
    return (unsigned short)((u + 0x7FFFu + ((u >> 16) & 1u)) >> 16);
}
__device__ __forceinline__ float bf16_to_f32(unsigned short b) {
    return __uint_as_float(((unsigned int)b) << 16);
}

// Kernel 1: wh = h @ W (fp32). Writes whB DIRECTLY in MFMA B-fragment order
// (bf16), plus src/dst PRE-SCALED by log2(e) so gat_attn uses bare v_exp_f32.
__global__ __launch_bounds__(256) void gat_prep(
    const float* __restrict__ h,      // 8192x128
    const float* __restrict__ edge,   // 8192x1
    const float* __restrict__ weight, // 128x64
    const float* __restrict__ att,    // 192x1
    const float* __restrict__ wedge,  // 1x64
    unsigned short* __restrict__ whB, // bf16 fragment-order (1 MB)
    float* __restrict__ src,          // 8192 (scaled by log2e)
    float* __restrict__ dst)          // 8192 (scaled by log2e)
{
    __shared__ float wl[FIN * FOUT];   // 32 KB
    __shared__ float hl[16 * FIN];     // 8 KB
    const int tid = threadIdx.x;
    const int b = blockIdx.x;

    const float4* w4 = (const float4*)weight;
    float4* wl4 = (float4*)wl;
    for (int idx = tid; idx < FIN * FOUT / 4; idx += 256) wl4[idx] = w4[idx];
    const float4* h4 = (const float4*)(h + (size_t)b * 16 * FIN);
    float4* hl4 = (float4*)hl;
    for (int idx = tid; idx < 16 * FIN / 4; idx += 256) hl4[idx] = h4[idx];
    __syncthreads();

    const int wave = tid >> 6;
    const int lane = tid & 63;
    float acc[4] = {0.f, 0.f, 0.f, 0.f};
    for (int c = 0; c < FIN; ++c) {
        const float wv = wl[c * FOUT + lane];
#pragma unroll
        for (int r = 0; r < 4; ++r)
            acc[r] = fmaf(hl[(wave * 4 + r) * FIN + c], wv, acc[r]);
    }
    const int row0 = b * 16 + wave * 4;

    // ---- whB fragment-order store (layout verified in prior session) ----
    {
        const int T = b >> 2;
        const int o = (b & 3) * 16 + wave * 4;     // tile-local row of r=0
        const int c = o >> 5;
        const int quad = (o >> 3) & 3;
        const int i0 = o & 7;                      // 0 or 4
        const int q = lane >> 4, col = lane & 15;
        const int f = T * 8 + q * 2 + c;
        const int elem = f * 64 + quad * 16 + col;
        ushort4v wb;
#pragma unroll
        for (int r = 0; r < 4; ++r) wb[r] = f32_to_bf16(acc[r]);
        *(ushort4v*)(whB + (size_t)elem * 8 + i0) = wb;
    }

    const float a1 = att[lane];
    const float a2 = att[FOUT + lane];
    float t3 = wedge[lane] * att[2 * FOUT + lane];
#pragma unroll
    for (int off = 32; off > 0; off >>= 1) t3 += __shfl_xor(t3, off, 64);

#pragma unroll
    for (int r = 0; r < 4; ++r) {
        float t1 = acc[r] * a1;
        float t2 = acc[r] * a2;
#pragma unroll
        for (int off = 32; off > 0; off >>= 1) {
            t1 += __shfl_xor(t1, off, 64);
            t2 += __shfl_xor(t2, off, 64);
        }
        if (lane == 0) {
            src[row0 + r] = (t1 + edge[row0 + r] * t3) * LOG2E;
            dst[row0 + r] = t2 * LOG2E;
        }
    }
}

// Kernel 1b: compress adj (256 MB int32) -> bitmask (8 MB), NATURAL bit order:
// word w of a row holds j = w*64 + bit. Achieved with 4 strided dword loads
// (each 256B coalesced) + 4 ballots per 256-j group. Pure streaming, BW-bound.
__global__ __launch_bounds__(256) void gat_mask(
    const int* __restrict__ adj, u64* __restrict__ mask)
{
    const int w = threadIdx.x >> 6, lane = threadIdx.x & 63;
    const int row = blockIdx.x * 4 + w;
    const int* a = adj + (size_t)row * NN;
    u64* mrow = mask + (size_t)row * MWPR;
#pragma unroll 4
    for (int g = 0; g < 32; ++g) {
        const int j0 = g * 256;
        const u64 b0 = __ballot(a[j0 + lane] > 0);
        const u64 b1 = __ballot(a[j0 + 64 + lane] > 0);
        const u64 b2 = __ballot(a[j0 + 128 + lane] > 0);
        const u64 b3 = __ballot(a[j0 + 192 + lane] > 0);
        if (lane < 4) {
            const u64 bb = lane == 0 ? b0 : lane == 1 ? b1 : lane == 2 ? b2 : b3;
            mrow[g * 4 + lane] = bb;
        }
    }
}

// Kernel 2: fused masked-softmax-numerator + P@Wh via MFMA.
// BARRIER-FREE inner loop: each wave owns all 16 i-rows x a PRIVATE 512-j
// range (lane = (row m, j-quad q); computes P[m][q*16..q*16+15]). The
// P->A-fragment transpose goes through a wave-private 2KB LDS tile
// (chunk-XOR swizzle -> uniform bank spread); the only ordering constraint
// is the wave's own in-order DS pipe. No s_barrier, no cross-wave coupling,
// no waitcnt pins: waves pipeline independently and the compiler is free to
// hoist next-microtile loads. One __syncthreads() at the end for the
// cross-wave j-partial reduction (ws_acc layout unchanged: [4][8192][64]).
__global__ __launch_bounds__(256) void gat_attn(
    const u64* __restrict__ mask,
    const unsigned short* __restrict__ whB,
    const float* __restrict__ src,
    const float* __restrict__ dst,
    float* __restrict__ ws_acc,      // [4][8192][64]
    float* __restrict__ ws_l)        // [4][8192]
{
    __shared__ unsigned short Pt[4][16][64];   // 8 KB, wave-private 2KB tiles
    __shared__ float red[4][16][64];           // 16 KB, epilogue reduce
    __shared__ float red_l[4][16];
    const int tid = threadIdx.x;
    const int w = tid >> 6, lane = tid & 63;
    const int m = lane & 15, q = lane >> 4;
    const int i0 = blockIdx.x * 16;
    const int s = blockIdx.y;
    const int Tbase = s * 32 + w * 8;          // 64-j tile index base for wave

    const float srm = src[i0 + m];
    const u64* mrow = mask + (size_t)(i0 + m) * MWPR + Tbase;
    const float4* dstq = (const float4*)(dst + (size_t)s * JSLICE + w * WJ) + q * 4;
    const short8* whB8 = (const short8*)whB;
    unsigned short* pt = &Pt[w][0][0];
    const int xm = m & 7;                      // chunk-XOR key

    floatx4 acc[4];
#pragma unroll
    for (int fg = 0; fg < 4; ++fg) acc[fg] = (floatx4){0.f, 0.f, 0.f, 0.f};
    float lsum = 0.f;

    for (int mt = 0; mt < NMT; ++mt) {
        // ---- B-fragments for this microtile (L2-hit; issue early)
        short8 bq[2][4];
        const int fb = (Tbase + mt) * 8;
#pragma unroll
        for (int c = 0; c < 2; ++c)
#pragma unroll
            for (int fg = 0; fg < 4; ++fg)
                bq[c][fg] = whB8[(size_t)(fb + fg * 2 + c) * 64 + lane];

        // ---- mask word + dst values for lane's 16 j's
        const u64 mw = mrow[mt];
        const unsigned int bits = (unsigned int)(mw >> (q * 16)) & 0xFFFFu;
        float dvf[16];
#pragma unroll
        for (int f = 0; f < 4; ++f) {
            const float4 t = dstq[mt * 16 + f];
            dvf[f * 4 + 0] = t.x; dvf[f * 4 + 1] = t.y;
            dvf[f * 4 + 2] = t.z; dvf[f * 4 + 3] = t.w;
        }

        // ---- exp + pack 16 elements (row m, j = q*16 + jj)
        unsigned int pk[8];
#pragma unroll
        for (int p2 = 0; p2 < 8; ++p2) {
            float v0 = srm + dvf[2 * p2];     v0 = fmaxf(v0, 0.2f * v0);
            float v1 = srm + dvf[2 * p2 + 1]; v1 = fmaxf(v1, 0.2f * v1);
            const float e0 = ((bits >> (2 * p2)) & 1u) ? __builtin_amdgcn_exp2f(v0) : 0.f;
            const float e1 = ((bits >> (2 * p2 + 1)) & 1u) ? __builtin_amdgcn_exp2f(v1) : 0.f;
            const unsigned int u0 = f32_to_bf16(e0);
            const unsigned int u1 = f32_to_bf16(e1);
            lsum += bf16_to_f32((unsigned short)u0) + bf16_to_f32((unsigned short)u1);
            pk[p2] = u0 | (u1 << 16);
        }

        // ---- wave-private LDS write, chunk-XOR swizzled (uniform banks)
        {
            uint4 t0; t0.x = pk[0]; t0.y = pk[1]; t0.z = pk[2]; t0.w = pk[3];
            uint4 t1; t1.x = pk[4]; t1.y = pk[5]; t1.z = pk[6]; t1.w = pk[7];
            *(uint4*)&pt[m * 64 + ((2 * q) ^ xm) * 8] = t0;
            *(uint4*)&pt[m * 64 + ((2 * q + 1) ^ xm) * 8] = t1;
        }

        // ---- 8 MFMAs over K=64 (in-order DS pipe guarantees RAW; no barrier)
#pragma unroll
        for (int c = 0; c < 2; ++c) {
            const short8 a = *(const short8*)&pt[m * 64 + (((c << 2) | q) ^ xm) * 8];
#pragma unroll
            for (int fg = 0; fg < 4; ++fg)
                acc[fg] = __builtin_amdgcn_mfma_f32_16x16x32_bf16(a, bq[c][fg], acc[fg], 0, 0, 0);
        }
    }

    // ---- reduce lsum over the 4 j-quads (lanes m, m+16, m+32, m+48)
    lsum += __shfl_xor(lsum, 16, 64);
    lsum += __shfl_xor(lsum, 32, 64);
    if (q == 0) red_l[w][m] = lsum;

    // ---- stash per-wave partial C (C/D layout: col=lane&15, row=q*4+reg)
#pragma unroll
    for (int fg = 0; fg < 4; ++fg)
#pragma unroll
        for (int reg = 0; reg < 4; ++reg)
            red[w][q * 4 + reg][fg * 16 + m] = acc[fg][reg];

    __syncthreads();

    // ---- cross-wave reduce + store
    if (tid < 16)
        ws_l[(size_t)s * NN + i0 + tid] =
            red_l[0][tid] + red_l[1][tid] + red_l[2][tid] + red_l[3][tid];
    {
        const int row = tid >> 4, f4 = tid & 15;
        float4 a = *(float4*)&red[0][row][f4 * 4];
#pragma unroll
        for (int ww = 1; ww < 4; ++ww) {
            const float4 b = *(float4*)&red[ww][row][f4 * 4];
            a.x += b.x; a.y += b.y; a.z += b.z; a.w += b.w;
        }
        ((float4*)ws_acc)[(size_t)s * (NN * 16) + (size_t)(i0 + row) * 16 + f4] = a;
    }
}

// Kernel 3: reduce 4 j-slices, divide by softmax denom, ELU. float4-vectorized.
__global__ __launch_bounds__(256) void gat_finish(
    const float* __restrict__ ws_acc, const float* __restrict__ ws_l,
    float* __restrict__ out)
{
    const int idx = blockIdx.x * 256 + threadIdx.x;   // float4 index, 0..NN*16-1
    const int i = idx >> 4;                            // 16 float4 per row
    float4 a = ((const float4*)ws_acc)[idx];
    float l = ws_l[i];
#pragma unroll
    for (int s = 1; s < NSLICE; ++s) {
        const float4 b = ((const float4*)ws_acc)[(size_t)s * (NN * 16) + idx];
        a.x += b.x; a.y += b.y; a.z += b.z; a.w += b.w;
        l += ws_l[(size_t)s * NN + i];
    }
    float4 o;
    float v;
    v = a.x / l; o.x = (v > 0.f) ? v : expm1f(v);
    v = a.y / l; o.y = (v > 0.f) ? v : expm1f(v);
    v = a.z / l; o.z = (v > 0.f) ? v : expm1f(v);
    v = a.w / l; o.w = (v > 0.f) ? v : expm1f(v);
    ((float4*)out)[idx] = o;
}

extern "C" void kernel_launch(void* const* d_in, const int* in_sizes, int n_in,
                              void* d_out, int out_size, void* d_ws, size_t ws_size,
                              hipStream_t stream) {
    const float* h      = (const float*)d_in[0];
    const float* edge   = (const float*)d_in[1];
    const int*   adj    = (const int*)d_in[2];
    const float* weight = (const float*)d_in[3];
    const float* att    = (const float*)d_in[4];
    const float* wedge  = (const float*)d_in[5];
    float* out = (float*)d_out;

    unsigned short* whB = (unsigned short*)d_ws;          // 1 MB bf16 frags
    float* src    = (float*)(whB + (size_t)NN * FOUT);    // 8192
    float* dst    = src + NN;                             // 8192
    float* ws_l   = dst + NN;                             // 4*8192
    float* ws_acc = ws_l + (size_t)NSLICE * NN;           // 8 MB
    u64*   mask   = (u64*)(ws_acc + (size_t)NSLICE * NN * FOUT);  // 8 MB

    gat_prep<<<NN / 16, 256, 0, stream>>>(h, edge, weight, att, wedge, whB, src, dst);
    gat_mask<<<NN / 4, 256, 0, stream>>>(adj, mask);
    gat_attn<<<dim3(NN / 16, NSLICE), 256, 0, stream>>>(mask, whB, src, dst, ws_acc, ws_l);
    gat_finish<<<NN * 16 / 256, 256, 0, stream>>>(ws_acc, ws_l, out);
}

// Round 3
// 376.447 us; speedup vs baseline: 1.1204x; 1.1042x over previous
//
#include <hip/hip_runtime.h>

#define NN 8192
#define FIN 128
#define FOUT 64
#define NSLICE 4
#define JSLICE (NN / NSLICE)
#define JTILE 256
#define NT (JSLICE / JTILE)   // 8 tiles per block
#define PT_LD 264             // Pt row stride in shorts: 256 + 8 pad
#define LOG2E 1.4426950408889634f

typedef __attribute__((ext_vector_type(8))) short short8;
typedef __attribute__((ext_vector_type(4))) float floatx4;
typedef __attribute__((ext_vector_type(4))) unsigned short ushort4v;

__device__ __forceinline__ unsigned short f32_to_bf16(float f) {
    unsigned int u = __float_as_uint(f);
    return (unsigned short)((u + 0x7FFFu + ((u >> 16) & 1u)) >> 16);
}
__device__ __forceinline__ float bf16_to_f32(unsigned short b) {
    return __uint_as_float(((unsigned int)b) << 16);
}

// Kernel 1: wh = h @ W (fp32). Writes whB DIRECTLY in MFMA B-fragment order
// (bf16), plus src/dst PRE-SCALED by log2(e) so gat_attn uses bare v_exp_f32:
// exp(leaky(x)) == exp2(leaky(x*log2e)) since log2e > 0 commutes with max().
__global__ __launch_bounds__(256) void gat_prep(
    const float* __restrict__ h,      // 8192x128
    const float* __restrict__ edge,   // 8192x1
    const float* __restrict__ weight, // 128x64
    const float* __restrict__ att,    // 192x1
    const float* __restrict__ wedge,  // 1x64
    unsigned short* __restrict__ whB, // bf16 fragment-order (1 MB)
    float* __restrict__ src,          // 8192 (scaled by log2e)
    float* __restrict__ dst)          // 8192 (scaled by log2e)
{
    __shared__ float wl[FIN * FOUT];   // 32 KB
    __shared__ float hl[16 * FIN];     // 8 KB
    const int tid = threadIdx.x;
    const int b = blockIdx.x;

    const float4* w4 = (const float4*)weight;
    float4* wl4 = (float4*)wl;
    for (int idx = tid; idx < FIN * FOUT / 4; idx += 256) wl4[idx] = w4[idx];
    const float4* h4 = (const float4*)(h + (size_t)b * 16 * FIN);
    float4* hl4 = (float4*)hl;
    for (int idx = tid; idx < 16 * FIN / 4; idx += 256) hl4[idx] = h4[idx];
    __syncthreads();

    const int wave = tid >> 6;
    const int lane = tid & 63;
    float acc[4] = {0.f, 0.f, 0.f, 0.f};
    for (int c = 0; c < FIN; ++c) {
        const float wv = wl[c * FOUT + lane];
#pragma unroll
        for (int r = 0; r < 4; ++r)
            acc[r] = fmaf(hl[(wave * 4 + r) * FIN + c], wv, acc[r]);
    }
    const int row0 = b * 16 + wave * 4;

    // ---- whB fragment-order store (layout verified in prior session) ----
    {
        const int T = b >> 2;
        const int o = (b & 3) * 16 + wave * 4;     // tile-local row of r=0
        const int c = o >> 5;
        const int quad = (o >> 3) & 3;
        const int i0 = o & 7;                      // 0 or 4
        const int q = lane >> 4, col = lane & 15;
        const int f = T * 8 + q * 2 + c;
        const int elem = f * 64 + quad * 16 + col;
        ushort4v wb;
#pragma unroll
        for (int r = 0; r < 4; ++r) wb[r] = f32_to_bf16(acc[r]);
        *(ushort4v*)(whB + (size_t)elem * 8 + i0) = wb;
    }

    const float a1 = att[lane];
    const float a2 = att[FOUT + lane];
    float t3 = wedge[lane] * att[2 * FOUT + lane];
#pragma unroll
    for (int off = 32; off > 0; off >>= 1) t3 += __shfl_xor(t3, off, 64);

#pragma unroll
    for (int r = 0; r < 4; ++r) {
        float t1 = acc[r] * a1;
        float t2 = acc[r] * a2;
#pragma unroll
        for (int off = 32; off > 0; off >>= 1) {
            t1 += __shfl_xor(t1, off, 64);
            t2 += __shfl_xor(t2, off, 64);
        }
        if (lane == 0) {
            src[row0 + r] = (t1 + edge[row0 + r] * t3) * LOG2E;
            dst[row0 + r] = t2 * LOG2E;
        }
    }
}

// Kernel 2: fused masked-softmax-numerator + P@Wh via MFMA, single pass over
// adj (the mandatory 256 MB HBM stream -- this kernel IS the roofline term).
// Per 256-j tile: exp-compute from prefetched regs -> LDS (double-buffered);
// B-fragment loads for THIS tile issued before the next-tile adj/dst prefetch
// (older in vmcnt order => MFMA's waits drain only L2-hit bq loads, the HBM
// prefetch stays in flight across the barrier); raw lgkmcnt(0)+s_barrier (no
// vmcnt drain); 8 MFMAs on dual accumulators. buf[t&1] is rewritten only at
// t+2, after barrier t+1, by which time tile-t LDS reads are consumed.
__global__ __launch_bounds__(256) void gat_attn(
    const int* __restrict__ adj,
    const unsigned short* __restrict__ whB,
    const float* __restrict__ src,
    const float* __restrict__ dst,
    float* __restrict__ ws_acc,      // [4][8192][64]
    float* __restrict__ ws_l)        // [4][8192]
{
    __shared__ unsigned short Pt[2][16][PT_LD];   // 16.9 KB
    const int wave = threadIdx.x >> 6;
    const int lane = threadIdx.x & 63;
    const int i0 = blockIdx.x * 16;
    const int s  = blockIdx.y;
    const size_t jbase = (size_t)s * JSLICE;
    const int m = lane & 15, quad = lane >> 4;

    float sr[4];
    const int4* ap[4];
#pragma unroll
    for (int r = 0; r < 4; ++r) {
        sr[r] = src[i0 + wave * 4 + r];
        ap[r] = (const int4*)(adj + (size_t)(i0 + wave * 4 + r) * NN + jbase);
    }
    const float4* dst4 = (const float4*)(dst + jbase);
    float lsum[4] = {0.f, 0.f, 0.f, 0.f};
    floatx4 acc0 = {0.f, 0.f, 0.f, 0.f};
    floatx4 acc1 = {0.f, 0.f, 0.f, 0.f};

    // Preload tile 0
    int4 av[4];
    float4 dv = dst4[lane];
#pragma unroll
    for (int r = 0; r < 4; ++r) av[r] = ap[r][lane];

    for (int t = 0; t < NT; ++t) {
        const int buf = t & 1;

        // ---- exp-compute current tile from registers; write LDS
#pragma unroll
        for (int r = 0; r < 4; ++r) {
            ushort4v pv;
            float v, p;
            v = sr[r] + dv.x; v = fmaxf(v, 0.2f * v);
            p = (av[r].x > 0) ? __builtin_amdgcn_exp2f(v) : 0.f; pv.x = f32_to_bf16(p);
            v = sr[r] + dv.y; v = fmaxf(v, 0.2f * v);
            p = (av[r].y > 0) ? __builtin_amdgcn_exp2f(v) : 0.f; pv.y = f32_to_bf16(p);
            v = sr[r] + dv.z; v = fmaxf(v, 0.2f * v);
            p = (av[r].z > 0) ? __builtin_amdgcn_exp2f(v) : 0.f; pv.z = f32_to_bf16(p);
            v = sr[r] + dv.w; v = fmaxf(v, 0.2f * v);
            p = (av[r].w > 0) ? __builtin_amdgcn_exp2f(v) : 0.f; pv.w = f32_to_bf16(p);
            lsum[r] += bf16_to_f32(pv.x) + bf16_to_f32(pv.y)
                     + bf16_to_f32(pv.z) + bf16_to_f32(pv.w);
            *(ushort4v*)&Pt[buf][wave * 4 + r][4 * lane] = pv;
        }

        // ---- B-fragment loads for THIS tile (L2-hit); issued before the
        // prefetch so MFMA's vmcnt waits never drain next-tile HBM loads.
        const int jt0 = (int)((jbase + (size_t)t * JTILE) >> 6);
        short8 bq[8];
#pragma unroll
        for (int kk = 0; kk < 8; ++kk) {
            const int f = (jt0 + (kk >> 1)) * 8 + wave * 2 + (kk & 1);
            bq[kk] = *((const short8*)whB + (size_t)f * 64 + lane);
        }
        __builtin_amdgcn_sched_barrier(0);   // pin: bq issue stays here

        // ---- prefetch next tile's adj + dst (newest; stay in flight)
        if (t + 1 < NT) {
            const int o = (t + 1) * (JTILE / 4) + lane;
            dv = dst4[o];
#pragma unroll
            for (int r = 0; r < 4; ++r) av[r] = ap[r][o];
        }

        // ---- LDS-visibility barrier only (no vmcnt drain)
        __builtin_amdgcn_s_waitcnt(0xC07F);   // lgkmcnt(0)
        __builtin_amdgcn_s_barrier();

        // ---- 8 MFMAs over K=256, dual accumulators
#pragma unroll
        for (int kk = 0; kk < 8; ++kk) {
            const short8 a = *(const short8*)&Pt[buf][m][kk * 32 + quad * 8];
            if (kk & 1)
                acc1 = __builtin_amdgcn_mfma_f32_16x16x32_bf16(a, bq[kk], acc1, 0, 0, 0);
            else
                acc0 = __builtin_amdgcn_mfma_f32_16x16x32_bf16(a, bq[kk], acc0, 0, 0, 0);
        }
    }

#pragma unroll
    for (int r = 0; r < 4; ++r) {
#pragma unroll
        for (int off = 32; off > 0; off >>= 1)
            lsum[r] += __shfl_xor(lsum[r], off, 64);
    }
    if (lane == 0) {
#pragma unroll
        for (int r = 0; r < 4; ++r)
            ws_l[(size_t)s * NN + i0 + wave * 4 + r] = lsum[r];
    }

    const floatx4 acc = acc0 + acc1;
    // C/D layout: col = lane&15, row = quad*4 + reg
#pragma unroll
    for (int reg = 0; reg < 4; ++reg) {
        const int row = quad * 4 + reg;
        ws_acc[(size_t)s * (NN * FOUT) + (size_t)(i0 + row) * FOUT + wave * 16 + m] = acc[reg];
    }
}

// Kernel 3: reduce 4 j-slices, divide by softmax denom, ELU. float4-vectorized.
__global__ __launch_bounds__(256) void gat_finish(
    const float* __restrict__ ws_acc, const float* __restrict__ ws_l,
    float* __restrict__ out)
{
    const int idx = blockIdx.x * 256 + threadIdx.x;   // float4 index, 0..NN*16-1
    const int i = idx >> 4;                            // 16 float4 per row
    float4 a = ((const float4*)ws_acc)[idx];
    float l = ws_l[i];
#pragma unroll
    for (int s = 1; s < NSLICE; ++s) {
        const float4 b = ((const float4*)ws_acc)[(size_t)s * (NN * 16) + idx];
        a.x += b.x; a.y += b.y; a.z += b.z; a.w += b.w;
        l += ws_l[(size_t)s * NN + i];
    }
    float4 o;
    float v;
    v = a.x / l; o.x = (v > 0.f) ? v : expm1f(v);
    v = a.y / l; o.y = (v > 0.f) ? v : expm1f(v);
    v = a.z / l; o.z = (v > 0.f) ? v : expm1f(v);
    v = a.w / l; o.w = (v > 0.f) ? v : expm1f(v);
    ((float4*)out)[idx] = o;
}

extern "C" void kernel_launch(void* const* d_in, const int* in_sizes, int n_in,
                              void* d_out, int out_size, void* d_ws, size_t ws_size,
                              hipStream_t stream) {
    const float* h      = (const float*)d_in[0];
    const float* edge   = (const float*)d_in[1];
    const int*   adj    = (const int*)d_in[2];
    const float* weight = (const float*)d_in[3];
    const float* att    = (const float*)d_in[4];
    const float* wedge  = (const float*)d_in[5];
    float* out = (float*)d_out;

    unsigned short* whB = (unsigned short*)d_ws;          // 1 MB bf16 frags
    float* src    = (float*)(whB + (size_t)NN * FOUT);    // 8192
    float* dst    = src + NN;                             // 8192
    float* ws_l   = dst + NN;                             // 4*8192
    float* ws_acc = ws_l + (size_t)NSLICE * NN;           // 8 MB

    gat_prep<<<NN / 16, 256, 0, stream>>>(h, edge, weight, att, wedge, whB, src, dst);
    gat_attn<<<dim3(NN / 16, NSLICE), 256, 0, stream>>>(adj, whB, src, dst, ws_acc, ws_l);
    gat_finish<<<NN * 16 / 256, 256, 0, stream>>>(ws_acc, ws_l, out);
}